// Round 3
// baseline (978.900 us; speedup 1.0000x reference)
//
#include <hip/hip_runtime.h>
#include <cstdint>
#include <cstddef>

typedef __attribute__((ext_vector_type(8))) short bf16x8;
typedef __attribute__((ext_vector_type(4))) float f32x4;
typedef __attribute__((ext_vector_type(8))) unsigned short ushort8;

#define FIX_CAP 65536
#define MARGIN 0.025f

__device__ __forceinline__ unsigned short f2bf(float f) {
  union { float f; unsigned int u; } x; x.f = f;
  unsigned int r = (x.u + 0x7fffu + ((x.u >> 16) & 1u)) >> 16;  // RNE
  return (unsigned short)r;
}

// ---------------------------------------------------------------------------
// kprep: fused preprocessing.
//   blocks [0,2048)    : x  [32768,128] f32 -> xb bf16   (+ zero fixup cnt)
//   blocks [2048,2304) : W3 [128,4096]  f32 -> W3b bf16
//   blocks [2304,2560) : W1 [4096,128]  f32 -> w1h bf16
//   blocks [2560,2688) : const[k] = dot(W3[k,:], b2) + b3[k]
// ---------------------------------------------------------------------------
__global__ __launch_bounds__(256) void kprep(
    const float* __restrict__ x, const float* __restrict__ W3,
    const float* __restrict__ W1, const float* __restrict__ b2,
    const float* __restrict__ b3, unsigned short* __restrict__ xb,
    unsigned short* __restrict__ W3b, unsigned short* __restrict__ w1h,
    float* __restrict__ constv, int* __restrict__ cnt) {
  const int bid = blockIdx.x;
  const int t = threadIdx.x;
  if (bid < 2560) {
    const float* src;
    unsigned short* dst;
    size_t e;
    if (bid < 2048) {
      src = x; dst = xb; e = ((size_t)bid * 256 + t) * 8;
      if (bid == 0 && t == 0) cnt[0] = 0;
    } else if (bid < 2304) {
      src = W3; dst = W3b; e = ((size_t)(bid - 2048) * 256 + t) * 8;
    } else {
      src = W1; dst = w1h; e = ((size_t)(bid - 2304) * 256 + t) * 8;
    }
    float ff[8];
    *(float4*)&ff[0] = *(const float4*)(src + e);
    *(float4*)&ff[4] = *(const float4*)(src + e + 4);
    ushort8 v;
#pragma unroll
    for (int i = 0; i < 8; i++) v[i] = f2bf(ff[i]);
    *(ushort8*)(dst + e) = v;
  } else {
    __shared__ float red[4];
    int k = bid - 2560;
    float s = 0.f;
    for (int j = t; j < 4096; j += 256) s += W3[k * 4096 + j] * b2[j];
#pragma unroll
    for (int m = 1; m < 64; m <<= 1) s += __shfl_xor(s, m, 64);
    if ((t & 63) == 0) red[t >> 6] = s;
    __syncthreads();
    if (t == 0) constv[k] = red[0] + red[1] + red[2] + red[3] + b3[k];
  }
}

// ---------------------------------------------------------------------------
// kzero: zero Mt [4096,128] f32 (runs after k1_fix — Mt overlaps xb)
// ---------------------------------------------------------------------------
__global__ __launch_bounds__(256) void kzero(float* __restrict__ Mt) {
  int e = blockIdx.x * 256 + threadIdx.x;  // 512*256 = 131072 float4s
  ((float4*)Mt)[e] = (float4){0.f, 0.f, 0.f, 0.f};
}

// ---------------------------------------------------------------------------
// K1: o = xb @ w1h^T + b1 via single-product bf16 MFMA, fused per-segment
// top-2 argmax. Block = 64 rows, 4 waves; stages the x-tile once and loops
// 4 segments (seg = blockIdx.y*4+s). Wave w covers 64 rows x 64 cols of the
// segment. Near-ties (gap < MARGIN) -> exact fp32 fixup (proven path).
// ---------------------------------------------------------------------------
__global__ __launch_bounds__(256) void k1_mfma(
    const unsigned short* __restrict__ xb, const unsigned short* __restrict__ w1h,
    const float* __restrict__ b1, int* __restrict__ idxbuf,
    int* __restrict__ cnt, int* __restrict__ list) {
  __shared__ unsigned short xs[64 * 136];  // pad 136: near-conflict-free b128
  __shared__ float rv1[64 * 4];
  __shared__ int   ri1[64 * 4];
  __shared__ float rv2[64 * 4];

  const int t = threadIdx.x;
  const int r0 = blockIdx.x * 64;

  // ---- stage xb tile 64x128 bf16 (coalesced 16B chunks) ----
#pragma unroll
  for (int it = 0; it < 4; it++) {
    int ch = it * 256 + t;  // 1024 chunks of 8 shorts
    int row = ch >> 4, k8 = ch & 15;
    bf16x8 v = *(const bf16x8*)(xb + (size_t)(r0 + row) * 128 + k8 * 8);
    *(bf16x8*)&xs[row * 136 + k8 * 8] = v;
  }
  __syncthreads();

  const int lane = t & 63, wv = t >> 6;
  const int m = lane & 15, q = lane >> 4;

  for (int s = 0; s < 4; s++) {
    const int seg = blockIdx.y * 4 + s;
    const int cbase = seg * 256 + wv * 64;

    f32x4 acc[4][4];
#pragma unroll
    for (int mt = 0; mt < 4; mt++)
#pragma unroll
      for (int nt = 0; nt < 4; nt++) acc[mt][nt] = (f32x4){0.f, 0.f, 0.f, 0.f};

#pragma unroll
    for (int ks = 0; ks < 4; ks++) {
      const int k0 = ks * 32;
      bf16x8 a[4];
#pragma unroll
      for (int mt = 0; mt < 4; mt++)
        a[mt] = *(const bf16x8*)&xs[(mt * 16 + m) * 136 + k0 + q * 8];
      bf16x8 bh[4];
#pragma unroll
      for (int nt = 0; nt < 4; nt++)
        bh[nt] = *(const bf16x8*)(w1h + (size_t)(cbase + nt * 16 + m) * 128 + k0 + q * 8);
#pragma unroll
      for (int nt = 0; nt < 4; nt++)
#pragma unroll
        for (int mt = 0; mt < 4; mt++)
          acc[mt][nt] = __builtin_amdgcn_mfma_f32_16x16x32_bf16(a[mt], bh[nt], acc[mt][nt], 0, 0, 0);
    }

    // ---- bias + per-row top-2 over this wave's 64 cols ----
    float bias[4];
#pragma unroll
    for (int nt = 0; nt < 4; nt++) bias[nt] = b1[cbase + nt * 16 + m];

    float tv1[16], tv2[16];
    int ti1[16];
#pragma unroll
    for (int mt = 0; mt < 4; mt++) {
#pragma unroll
      for (int reg = 0; reg < 4; reg++) {
        float v1 = acc[mt][0][reg] + bias[0];
        int i1 = wv * 64 + m;
        float v2 = -3.4e38f;
#pragma unroll
        for (int nt = 1; nt < 4; nt++) {
          float u = acc[mt][nt][reg] + bias[nt];
          int j = wv * 64 + nt * 16 + m;
          if (u > v1) { v2 = v1; v1 = u; i1 = j; } else { v2 = fmaxf(v2, u); }
        }
        // butterfly across 16 lanes of the quarter (disjoint col sets)
#pragma unroll
        for (int msk = 1; msk <= 8; msk <<= 1) {
          float u1 = __shfl_xor(v1, msk, 64);
          int   j1 = __shfl_xor(i1, msk, 64);
          float u2 = __shfl_xor(v2, msk, 64);
          if (u1 > v1) { v2 = fmaxf(v1, u2); v1 = u1; i1 = j1; }
          else if (u1 == v1) { i1 = min(i1, j1); v2 = v1; }
          else { v2 = fmaxf(v2, u1); }
        }
        tv1[mt * 4 + reg] = v1; ti1[mt * 4 + reg] = i1; tv2[mt * 4 + reg] = v2;
      }
    }

    __syncthreads();  // previous iteration's merge reads complete
    if (m == 0) {
#pragma unroll
      for (int mt = 0; mt < 4; mt++)
#pragma unroll
        for (int reg = 0; reg < 4; reg++) {
          int rl = mt * 16 + q * 4 + reg;
          rv1[rl * 4 + wv] = tv1[mt * 4 + reg];
          ri1[rl * 4 + wv] = ti1[mt * 4 + reg];
          rv2[rl * 4 + wv] = tv2[mt * 4 + reg];
        }
    }
    __syncthreads();

    // ---- merge the 4 waves (disjoint 64-col ranges), emit idx + flag ----
    if (t < 64) {
      float v1 = rv1[t * 4], v2 = rv2[t * 4];
      int i1 = ri1[t * 4];
#pragma unroll
      for (int w = 1; w < 4; w++) {
        float u1 = rv1[t * 4 + w], u2 = rv2[t * 4 + w];
        int j1 = ri1[t * 4 + w];
        if (u1 > v1) { v2 = fmaxf(v1, u2); v1 = u1; i1 = j1; }
        else if (u1 == v1) { i1 = min(i1, j1); v2 = v1; }
        else { v2 = fmaxf(v2, u1); }
      }
      int b = r0 + t;
      idxbuf[b * 16 + seg] = i1;
      if (v1 - v2 < MARGIN) {
        int p = atomicAdd(cnt, 1);
        if (p < FIX_CAP) list[p] = (b << 4) | seg;
      }
    }
  }
}

// ---------------------------------------------------------------------------
// K1fix: for flagged (b,seg), recompute all 256 logits in EXACT baseline fp32
// order (acc = b1[c]; ascending-k fmaf) — proven to match numpy in r1/r2.
// W1 (2 MB) is L2-resident; x row reads are wave-broadcast.
// ---------------------------------------------------------------------------
__global__ __launch_bounds__(256) void k1_fix(
    const float* __restrict__ x, const float* __restrict__ W1,
    const float* __restrict__ b1, const int* __restrict__ cnt,
    const int* __restrict__ list, int* __restrict__ idxbuf) {
  __shared__ float redv[4];
  __shared__ int   redi[4];
  const int t = threadIdx.x;
  const int lane = t & 63, wv = t >> 6;
  int n = cnt[0]; if (n > FIX_CAP) n = FIX_CAP;
  for (int e = blockIdx.x; e < n; e += 256) {
    int pk = list[e];
    int b = pk >> 4, seg = pk & 15;
    int c = seg * 256 + t;
    float a = b1[c];
    const float4* xr = (const float4*)(x + (size_t)b * 128);
    const float4* wr = (const float4*)(W1 + (size_t)c * 128);
#pragma unroll 8
    for (int k4 = 0; k4 < 32; k4++) {
      float4 xv = xr[k4];
      float4 wv4 = wr[k4];
      a = fmaf(xv.x, wv4.x, a);
      a = fmaf(xv.y, wv4.y, a);
      a = fmaf(xv.z, wv4.z, a);
      a = fmaf(xv.w, wv4.w, a);
    }
    float v = a; int li = t;
#pragma unroll
    for (int msk = 1; msk < 64; msk <<= 1) {
      float u = __shfl_xor(v, msk, 64);
      int ju = __shfl_xor(li, msk, 64);
      if (u > v || (u == v && ju < li)) { v = u; li = ju; }
    }
    if (lane == 0) { redv[wv] = v; redi[wv] = li; }
    __syncthreads();
    if (t == 0) {
      float bv = redv[0]; int bi = redi[0];
#pragma unroll
      for (int w = 1; w < 4; w++) {
        if (redv[w] > bv || (redv[w] == bv && redi[w] < bi)) { bv = redv[w]; bi = redi[w]; }
      }
      idxbuf[b * 16 + seg] = bi;
    }
    __syncthreads();
  }
}

// ---------------------------------------------------------------------------
// K2: Mt[c,k] += sum_{j in chunk} W2[j,c]*W3b[k,j] via bf16 MFMA, split-K=8,
// atomic f32 accumulate into zeroed Mt (order jitter ~1e-7).
// ---------------------------------------------------------------------------
__global__ __launch_bounds__(256) void k2_mfma(const float* __restrict__ W2,
                                               const unsigned short* __restrict__ W3b,
                                               float* __restrict__ Mt) {
  const int t = threadIdx.x;
  const int lane = t & 63, wv = t >> 6;
  const int c0 = (blockIdx.x * 4 + wv) * 16;  // 64 blocks * 4 waves -> 4096 c
  const int jq = blockIdx.y;                  // 8 K-chunks of 512
  const int m = lane & 15, q = lane >> 4;
  f32x4 acc[8];
#pragma unroll
  for (int nt = 0; nt < 8; nt++) acc[nt] = (f32x4){0.f, 0.f, 0.f, 0.f};

  for (int it = 0; it < 16; it++) {
    const int j0 = jq * 512 + it * 32;
    union { bf16x8 v; unsigned short u[8]; } a;
    const float* ap = W2 + (size_t)(j0 + q * 8) * 4096 + c0 + m;
#pragma unroll
    for (int i = 0; i < 8; i++) a.u[i] = f2bf(ap[(size_t)i * 4096]);
#pragma unroll
    for (int nt = 0; nt < 8; nt++) {
      bf16x8 b = *(const bf16x8*)(W3b + (nt * 16 + m) * 4096 + j0 + q * 8);
      acc[nt] = __builtin_amdgcn_mfma_f32_16x16x32_bf16(a.v, b, acc[nt], 0, 0, 0);
    }
  }
#pragma unroll
  for (int nt = 0; nt < 8; nt++)
#pragma unroll
    for (int r = 0; r < 4; r++)
      atomicAdd(&Mt[(size_t)(c0 + q * 4 + r) * 128 + nt * 16 + m], acc[nt][r]);
}

// ---------------------------------------------------------------------------
// K3: out[b,k] = const[k] + sum_g Mt[g*256 + idx[b,g], k]
// ---------------------------------------------------------------------------
__global__ __launch_bounds__(256) void k3_gather(const int* __restrict__ idxbuf,
                                                 const float* __restrict__ Mt,
                                                 const float* __restrict__ constv,
                                                 float* __restrict__ out) {
  const int t = threadIdx.x;
  const int w = t >> 6;
  const int lane = t & 63;
  const int b = blockIdx.x * 4 + w;
  float a0 = constv[lane];
  float a1 = constv[lane + 64];
  const int* ib = idxbuf + b * 16;
  int cg[16];
#pragma unroll
  for (int g = 0; g < 16; g++) cg[g] = g * 256 + ib[g];
#pragma unroll
  for (int g = 0; g < 16; g++) {
    const float* mrow = Mt + (size_t)cg[g] * 128;
    a0 += mrow[lane];
    a1 += mrow[lane + 64];
  }
  out[b * 128 + lane] = a0;
  out[b * 128 + lane + 64] = a1;
}

// ---------------------------------------------------------------------------
extern "C" void kernel_launch(void* const* d_in, const int* in_sizes, int n_in,
                              void* d_out, int out_size, void* d_ws, size_t ws_size,
                              hipStream_t stream) {
  const float* x  = (const float*)d_in[0];   // [32768,128]
  const float* W1 = (const float*)d_in[1];   // [4096,128]
  const float* b1 = (const float*)d_in[2];   // [4096]
  const float* W2 = (const float*)d_in[3];   // [4096,4096]
  const float* b2 = (const float*)d_in[4];   // [4096]
  const float* W3 = (const float*)d_in[5];   // [128,4096]
  const float* b3 = (const float*)d_in[6];   // [128]
  float* out = (float*)d_out;                // [32768,128]

  // workspace layout (peak 12.5 MB):
  //   xb [8 MB] overlaps Mt [2 MB]: xb dead after k1_mfma; Mt zeroed after k1_fix.
  char* w = (char*)d_ws;
  int* idxbuf         = (int*)(w);                            // 0.0 - 2.0 MB
  unsigned short* W3b = (unsigned short*)(w + (2u << 20));    // 2.0 - 3.0 MB
  unsigned short* w1h = (unsigned short*)(w + (3u << 20));    // 3.0 - 4.0 MB
  float* constv       = (float*)(w + (4u << 20));             // 512 B
  int* cnt            = (int*)(w + (4u << 20) + 1024);        // 4 B
  int* fixlist        = (int*)(w + (4u << 20) + 4096);        // 256 KB
  unsigned short* xb  = (unsigned short*)(w + (9u << 21) / 2);// 4.5 - 12.5 MB
  float* Mt           = (float*)(w + (9u << 21) / 2);         // 4.5 - 6.5 MB (overlap)

  kprep<<<2688, 256, 0, stream>>>(x, W3, W1, b2, b3, xb, W3b, w1h, constv, cnt);
  k1_mfma<<<dim3(512, 4), 256, 0, stream>>>(xb, w1h, b1, idxbuf, cnt, fixlist);
  k1_fix<<<256, 256, 0, stream>>>(x, W1, b1, cnt, fixlist, idxbuf);
  kzero<<<512, 256, 0, stream>>>(Mt);
  k2_mfma<<<dim3(64, 8), 256, 0, stream>>>(W2, W3b, Mt);
  k3_gather<<<8192, 256, 0, stream>>>(idxbuf, Mt, constv, out);
}

// Round 4
// 483.649 us; speedup vs baseline: 2.0240x; 2.0240x over previous
//
#include <hip/hip_runtime.h>
#include <cstdint>
#include <cstddef>

typedef __attribute__((ext_vector_type(8))) short bf16x8;
typedef __attribute__((ext_vector_type(4))) float f32x4;
typedef __attribute__((ext_vector_type(8))) unsigned short ushort8;

#define FIX_CAP 65536
#define MARGIN 0.025f

__device__ __forceinline__ unsigned short f2bf(float f) {
  union { float f; unsigned int u; } x; x.f = f;
  unsigned int r = (x.u + 0x7fffu + ((x.u >> 16) & 1u)) >> 16;  // RNE
  return (unsigned short)r;
}

// ---------------------------------------------------------------------------
// kprep: fused preprocessing.
//   [0,2048)    : x  [32768,128] f32 -> xb bf16   (+ zero fixup cnt)
//   [2048,2304) : W3 [128,4096]  f32 -> W3b bf16
//   [2304,2560) : W1 [4096,128]  f32 -> w1h bf16
//   [2560,2624) : zero candn (256 KB)
//   [2624,2752) : const[k] = dot(W3[k,:], b2) + b3[k]
// ---------------------------------------------------------------------------
__global__ __launch_bounds__(256) void kprep(
    const float* __restrict__ x, const float* __restrict__ W3,
    const float* __restrict__ W1, const float* __restrict__ b2,
    const float* __restrict__ b3, unsigned short* __restrict__ xb,
    unsigned short* __restrict__ W3b, unsigned short* __restrict__ w1h,
    float* __restrict__ constv, int* __restrict__ cnt, int* __restrict__ candn) {
  const int bid = blockIdx.x;
  const int t = threadIdx.x;
  if (bid < 2560) {
    const float* src;
    unsigned short* dst;
    size_t e;
    if (bid < 2048) {
      src = x; dst = xb; e = ((size_t)bid * 256 + t) * 8;
      if (bid == 0 && t == 0) cnt[0] = 0;
    } else if (bid < 2304) {
      src = W3; dst = W3b; e = ((size_t)(bid - 2048) * 256 + t) * 8;
    } else {
      src = W1; dst = w1h; e = ((size_t)(bid - 2304) * 256 + t) * 8;
    }
    float ff[8];
    *(float4*)&ff[0] = *(const float4*)(src + e);
    *(float4*)&ff[4] = *(const float4*)(src + e + 4);
    ushort8 v;
#pragma unroll
    for (int i = 0; i < 8; i++) v[i] = f2bf(ff[i]);
    *(ushort8*)(dst + e) = v;
  } else if (bid < 2624) {
    int e = (bid - 2560) * 256 + t;  // 16384 int4s = 256 KB
    ((int4*)candn)[e] = make_int4(0, 0, 0, 0);
  } else {
    __shared__ float red[4];
    int k = bid - 2624;
    float s = 0.f;
    for (int j = t; j < 4096; j += 256) s += W3[k * 4096 + j] * b2[j];
#pragma unroll
    for (int m = 1; m < 64; m <<= 1) s += __shfl_xor(s, m, 64);
    if ((t & 63) == 0) red[t >> 6] = s;
    __syncthreads();
    if (t == 0) constv[k] = red[0] + red[1] + red[2] + red[3] + b3[k];
  }
}

// ---------------------------------------------------------------------------
// kzero: zero Mt [4096,128] f32 (runs after k1_fixc — Mt overlaps xb)
// ---------------------------------------------------------------------------
__global__ __launch_bounds__(256) void kzero(float* __restrict__ Mt) {
  int e = blockIdx.x * 256 + threadIdx.x;  // 512*256 = 131072 float4s
  ((float4*)Mt)[e] = (float4){0.f, 0.f, 0.f, 0.f};
}

// ---------------------------------------------------------------------------
// K1: o = xb @ w1h^T + b1 via bf16 MFMA, fused per-segment top-2 argmax.
// Near-tie rows (gap < MARGIN) are flagged, and ALL columns within MARGIN of
// the bulk max are appended (byte indices) to a per-slot candidate list for
// the exact-fp32 fixup. Block = 64 rows, 4 waves, 4 segments per staged tile.
// ---------------------------------------------------------------------------
__global__ __launch_bounds__(256) void k1_mfma(
    const unsigned short* __restrict__ xb, const unsigned short* __restrict__ w1h,
    const float* __restrict__ b1, int* __restrict__ idxbuf,
    int* __restrict__ cnt, int* __restrict__ list,
    int* __restrict__ candn, unsigned char* __restrict__ candby) {
  __shared__ unsigned short xs[64 * 136];
  __shared__ float rv1[64 * 4];
  __shared__ int   ri1[64 * 4];
  __shared__ float rv2[64 * 4];
  __shared__ float rowthr[64];
  __shared__ int   rowslot[64];

  const int t = threadIdx.x;
  const int r0 = blockIdx.x * 64;

  // ---- stage xb tile 64x128 bf16 ----
#pragma unroll
  for (int it = 0; it < 4; it++) {
    int ch = it * 256 + t;
    int row = ch >> 4, k8 = ch & 15;
    bf16x8 v = *(const bf16x8*)(xb + (size_t)(r0 + row) * 128 + k8 * 8);
    *(bf16x8*)&xs[row * 136 + k8 * 8] = v;
  }
  __syncthreads();

  const int lane = t & 63, wv = t >> 6;
  const int m = lane & 15, q = lane >> 4;

  for (int s = 0; s < 4; s++) {
    const int seg = blockIdx.y * 4 + s;
    const int cbase = seg * 256 + wv * 64;

    f32x4 acc[4][4];
#pragma unroll
    for (int mt = 0; mt < 4; mt++)
#pragma unroll
      for (int nt = 0; nt < 4; nt++) acc[mt][nt] = (f32x4){0.f, 0.f, 0.f, 0.f};

#pragma unroll
    for (int ks = 0; ks < 4; ks++) {
      const int k0 = ks * 32;
      bf16x8 a[4];
#pragma unroll
      for (int mt = 0; mt < 4; mt++)
        a[mt] = *(const bf16x8*)&xs[(mt * 16 + m) * 136 + k0 + q * 8];
      bf16x8 bh[4];
#pragma unroll
      for (int nt = 0; nt < 4; nt++)
        bh[nt] = *(const bf16x8*)(w1h + (size_t)(cbase + nt * 16 + m) * 128 + k0 + q * 8);
#pragma unroll
      for (int nt = 0; nt < 4; nt++)
#pragma unroll
        for (int mt = 0; mt < 4; mt++)
          acc[mt][nt] = __builtin_amdgcn_mfma_f32_16x16x32_bf16(a[mt], bh[nt], acc[mt][nt], 0, 0, 0);
    }

    // ---- bias + per-row top-2 over this wave's 64 cols ----
    float bias[4];
#pragma unroll
    for (int nt = 0; nt < 4; nt++) bias[nt] = b1[cbase + nt * 16 + m];

    float tv1[16], tv2[16];
    int ti1[16];
#pragma unroll
    for (int mt = 0; mt < 4; mt++) {
#pragma unroll
      for (int reg = 0; reg < 4; reg++) {
        float v1 = acc[mt][0][reg] + bias[0];
        int i1 = wv * 64 + m;
        float v2 = -3.4e38f;
#pragma unroll
        for (int nt = 1; nt < 4; nt++) {
          float u = acc[mt][nt][reg] + bias[nt];
          int j = wv * 64 + nt * 16 + m;
          if (u > v1) { v2 = v1; v1 = u; i1 = j; } else { v2 = fmaxf(v2, u); }
        }
#pragma unroll
        for (int msk = 1; msk <= 8; msk <<= 1) {
          float u1 = __shfl_xor(v1, msk, 64);
          int   j1 = __shfl_xor(i1, msk, 64);
          float u2 = __shfl_xor(v2, msk, 64);
          if (u1 > v1) { v2 = fmaxf(v1, u2); v1 = u1; i1 = j1; }
          else if (u1 == v1) { i1 = min(i1, j1); v2 = v1; }
          else { v2 = fmaxf(v2, u1); }
        }
        tv1[mt * 4 + reg] = v1; ti1[mt * 4 + reg] = i1; tv2[mt * 4 + reg] = v2;
      }
    }

    __syncthreads();  // prior iteration's LDS reads complete
    if (m == 0) {
#pragma unroll
      for (int mt = 0; mt < 4; mt++)
#pragma unroll
        for (int reg = 0; reg < 4; reg++) {
          int rl = mt * 16 + q * 4 + reg;
          rv1[rl * 4 + wv] = tv1[mt * 4 + reg];
          ri1[rl * 4 + wv] = ti1[mt * 4 + reg];
          rv2[rl * 4 + wv] = tv2[mt * 4 + reg];
        }
    }
    __syncthreads();

    // ---- merge 4 waves; emit idx, flag near-ties, publish row threshold ----
    if (t < 64) {
      float v1 = rv1[t * 4], v2 = rv2[t * 4];
      int i1 = ri1[t * 4];
#pragma unroll
      for (int w = 1; w < 4; w++) {
        float u1 = rv1[t * 4 + w], u2 = rv2[t * 4 + w];
        int j1 = ri1[t * 4 + w];
        if (u1 > v1) { v2 = fmaxf(v1, u2); v1 = u1; i1 = j1; }
        else if (u1 == v1) { i1 = min(i1, j1); v2 = v1; }
        else { v2 = fmaxf(v2, u1); }
      }
      int b = r0 + t;
      idxbuf[b * 16 + seg] = i1;
      int slot = -1;
      if (v1 - v2 < MARGIN) {
        int p = atomicAdd(cnt, 1);
        if (p < FIX_CAP) { list[p] = (b << 4) | seg; slot = p; }
      }
      rowslot[t] = slot;
      rowthr[t] = v1 - MARGIN;
    }
    __syncthreads();

    // ---- candidate scan: all threads check their 64 register values ----
#pragma unroll
    for (int mt = 0; mt < 4; mt++) {
#pragma unroll
      for (int reg = 0; reg < 4; reg++) {
        int row = mt * 16 + q * 4 + reg;
        int slot = rowslot[row];
        if (slot >= 0) {
          float thr = rowthr[row];
#pragma unroll
          for (int nt = 0; nt < 4; nt++) {
            float u = acc[mt][nt][reg] + bias[nt];
            if (u >= thr) {
              int pos = atomicAdd(&candn[slot], 1);
              if (pos < 8) candby[slot * 8 + pos] = (unsigned char)(wv * 64 + nt * 16 + m);
            }
          }
        }
      }
    }
  }
}

// ---------------------------------------------------------------------------
// K1fixc: one wave per flagged (b,seg). Candidate path (<=8 cols): each lane
// computes ONE exact baseline-fp32 dot (b1 init, ascending-k fmaf — the
// numerics proven to match numpy in r1-r3); pick max, lowest-col tiebreak.
// Fallback (>8 candidates, rare): full 256-col exact recompute, 4 cols/lane.
// ---------------------------------------------------------------------------
__global__ __launch_bounds__(256) void k1_fixc(
    const float* __restrict__ x, const float* __restrict__ W1,
    const float* __restrict__ b1, const int* __restrict__ cnt,
    const int* __restrict__ list, const int* __restrict__ candn,
    const unsigned char* __restrict__ candby, int* __restrict__ idxbuf) {
  const int t = threadIdx.x;
  const int lane = t & 63, wv = t >> 6;
  const int wid = blockIdx.x * 4 + wv;
  int n = cnt[0]; if (n > FIX_CAP) n = FIX_CAP;
  for (int e = wid; e < n; e += 4096) {
    int pk = list[e];
    int b = pk >> 4, seg = pk & 15;
    int nc = candn[e];
    const float4* xr = (const float4*)(x + (size_t)b * 128);
    float bestv = -3.4e38f;
    int bestc = 0x7fffffff;
    if (nc <= 8) {
      if (lane < nc) {
        int col = candby[e * 8 + lane];
        int c = seg * 256 + col;
        float a = b1[c];
        const float4* wr = (const float4*)(W1 + (size_t)c * 128);
#pragma unroll 8
        for (int k4 = 0; k4 < 32; k4++) {
          float4 xv = xr[k4];
          float4 wv4 = wr[k4];
          a = fmaf(xv.x, wv4.x, a);
          a = fmaf(xv.y, wv4.y, a);
          a = fmaf(xv.z, wv4.z, a);
          a = fmaf(xv.w, wv4.w, a);
        }
        bestv = a; bestc = col;
      }
    } else {
#pragma unroll
      for (int j = 0; j < 4; j++) {
        int col = lane * 4 + j;
        int c = seg * 256 + col;
        float a = b1[c];
        const float4* wr = (const float4*)(W1 + (size_t)c * 128);
        for (int k4 = 0; k4 < 32; k4++) {
          float4 xv = xr[k4];
          float4 wv4 = wr[k4];
          a = fmaf(xv.x, wv4.x, a);
          a = fmaf(xv.y, wv4.y, a);
          a = fmaf(xv.z, wv4.z, a);
          a = fmaf(xv.w, wv4.w, a);
        }
        if (a > bestv) { bestv = a; bestc = col; }  // ascending col keeps lowest
      }
    }
#pragma unroll
    for (int msk = 1; msk < 64; msk <<= 1) {
      float u = __shfl_xor(bestv, msk, 64);
      int uc = __shfl_xor(bestc, msk, 64);
      if (u > bestv || (u == bestv && uc < bestc)) { bestv = u; bestc = uc; }
    }
    if (lane == 0) idxbuf[b * 16 + seg] = bestc;
  }
}

// ---------------------------------------------------------------------------
// K2: Mt[c,k] += sum_{j in chunk} W2[j,c]*W3b[k,j] via bf16 MFMA, split-K=8,
// atomic f32 accumulate into zeroed Mt.
// ---------------------------------------------------------------------------
__global__ __launch_bounds__(256) void k2_mfma(const float* __restrict__ W2,
                                               const unsigned short* __restrict__ W3b,
                                               float* __restrict__ Mt) {
  const int t = threadIdx.x;
  const int lane = t & 63, wv = t >> 6;
  const int c0 = (blockIdx.x * 4 + wv) * 16;
  const int jq = blockIdx.y;
  const int m = lane & 15, q = lane >> 4;
  f32x4 acc[8];
#pragma unroll
  for (int nt = 0; nt < 8; nt++) acc[nt] = (f32x4){0.f, 0.f, 0.f, 0.f};

  for (int it = 0; it < 16; it++) {
    const int j0 = jq * 512 + it * 32;
    union { bf16x8 v; unsigned short u[8]; } a;
    const float* ap = W2 + (size_t)(j0 + q * 8) * 4096 + c0 + m;
#pragma unroll
    for (int i = 0; i < 8; i++) a.u[i] = f2bf(ap[(size_t)i * 4096]);
#pragma unroll
    for (int nt = 0; nt < 8; nt++) {
      bf16x8 b = *(const bf16x8*)(W3b + (nt * 16 + m) * 4096 + j0 + q * 8);
      acc[nt] = __builtin_amdgcn_mfma_f32_16x16x32_bf16(a.v, b, acc[nt], 0, 0, 0);
    }
  }
#pragma unroll
  for (int nt = 0; nt < 8; nt++)
#pragma unroll
    for (int r = 0; r < 4; r++)
      atomicAdd(&Mt[(size_t)(c0 + q * 4 + r) * 128 + nt * 16 + m], acc[nt][r]);
}

// ---------------------------------------------------------------------------
// K3: out[b,k] = const[k] + sum_g Mt[g*256 + idx[b,g], k]
// ---------------------------------------------------------------------------
__global__ __launch_bounds__(256) void k3_gather(const int* __restrict__ idxbuf,
                                                 const float* __restrict__ Mt,
                                                 const float* __restrict__ constv,
                                                 float* __restrict__ out) {
  const int t = threadIdx.x;
  const int w = t >> 6;
  const int lane = t & 63;
  const int b = blockIdx.x * 4 + w;
  float a0 = constv[lane];
  float a1 = constv[lane + 64];
  const int* ib = idxbuf + b * 16;
  int cg[16];
#pragma unroll
  for (int g = 0; g < 16; g++) cg[g] = g * 256 + ib[g];
#pragma unroll
  for (int g = 0; g < 16; g++) {
    const float* mrow = Mt + (size_t)cg[g] * 128;
    a0 += mrow[lane];
    a1 += mrow[lane + 64];
  }
  out[b * 128 + lane] = a0;
  out[b * 128 + lane + 64] = a1;
}

// ---------------------------------------------------------------------------
extern "C" void kernel_launch(void* const* d_in, const int* in_sizes, int n_in,
                              void* d_out, int out_size, void* d_ws, size_t ws_size,
                              hipStream_t stream) {
  const float* x  = (const float*)d_in[0];   // [32768,128]
  const float* W1 = (const float*)d_in[1];   // [4096,128]
  const float* b1 = (const float*)d_in[2];   // [4096]
  const float* W2 = (const float*)d_in[3];   // [4096,4096]
  const float* b2 = (const float*)d_in[4];   // [4096]
  const float* W3 = (const float*)d_in[5];   // [128,4096]
  const float* b3 = (const float*)d_in[6];   // [128]
  float* out = (float*)d_out;                // [32768,128]

  // workspace (peak 13.25 MB; xb dead after k1_fixc, Mt overlaps it)
  char* w = (char*)d_ws;
  int* idxbuf          = (int*)(w);                                   // 0 - 2 MB
  unsigned short* W3b  = (unsigned short*)(w + (2u << 20));           // 2 - 3 MB
  unsigned short* w1h  = (unsigned short*)(w + (3u << 20));           // 3 - 4 MB
  float* constv        = (float*)(w + (4u << 20));                    // 512 B
  int* cnt             = (int*)(w + (4u << 20) + 1024);               // 4 B
  int* fixlist         = (int*)(w + (4u << 20) + 4096);               // 256 KB
  int* candn           = (int*)(w + (4u << 20) + 4096 + (256u << 10));// 256 KB
  unsigned char* candby= (unsigned char*)(w + (4u << 20) + 4096 + (512u << 10)); // 512 KB
  unsigned short* xb   = (unsigned short*)(w + 5505024u);             // 5.25 - 13.25 MB
  float* Mt            = (float*)(w + 5505024u);                      // 5.25 - 7.25 MB (overlap)

  kprep<<<2752, 256, 0, stream>>>(x, W3, W1, b2, b3, xb, W3b, w1h, constv, cnt, candn);
  k1_mfma<<<dim3(512, 4), 256, 0, stream>>>(xb, w1h, b1, idxbuf, cnt, fixlist, candn, candby);
  k1_fixc<<<1024, 256, 0, stream>>>(x, W1, b1, cnt, fixlist, candn, candby, idxbuf);
  kzero<<<512, 256, 0, stream>>>(Mt);
  k2_mfma<<<dim3(64, 8), 256, 0, stream>>>(W2, W3b, Mt);
  k3_gather<<<8192, 256, 0, stream>>>(idxbuf, Mt, constv, out);
}